// Round 5
// baseline (397.396 us; speedup 1.0000x reference)
//
#include <hip/hip_runtime.h>
#include <hip/hip_cooperative_groups.h>
#include <math.h>

namespace cg = cooperative_groups;

// Cone-beam forward projection (TIGRE Ax analogue).
// Volume: [B=2, NZ=96, NY=96, NX=96] f32, ZYX layout (x fastest).
// Output: [B=2, A=48, NV=96, NU=96] f32.
//
// R15: main loop is TA-throughput-bound at its structural floor
// (4 gathers/sample x (16 addr-cycles + ~29 lines) -- validated across
// R10/R13/R14: occupancy 49->74% changes nothing, lines model predicts
// durations within 5%). Remaining addressable cost was the ~50us of
// inter-dispatch serialization (R10: 49us gap for a 4us pack). Fix:
// ONE cooperative kernel = pack phase + grid.sync + R13 projection body
// (verbatim). make_trig stays separate (keeps f64 trig VGPRs out of the
// cooperative kernel so co-residency validation passes). Fallback to the
// measured 3-launch R13 path if cooperative launch is rejected.
//
// CORRECTNESS-CRITICAL: reference integrand is DISCONTINUOUS at cube faces.
// Position path replicates the reference's f32 op sequence exactly:
// contract(off), per-sample src + d*t, IEEE sqrt+div, f64-rounded trig.

#define NZg 96
#define NYg 96
#define NXg 96
#define NVg 96
#define NUg 96
#define NAg 48
#define NSg 96
#define NBg 2
#define NVOX (NZg * NYg * NXg)          // 884736 voxels per batch
#define NRAY1 (NAg * NVg * NUg)         // 442368 rays per batch
#define PLANE (NYg * NXg)               // 9216 float2 elements per z-plane
#define NBLK 1728                       // NRAY1 / 256 (co-resident grid)

typedef float v4f __attribute__((ext_vector_type(4)));  // default (16B) align

// ---------------- per-angle trig table (bit-identical to inline calc) -----
__global__ void make_trig(float2* __restrict__ trig) {
    const int a = threadIdx.x;
    if (a < NAg) {
        const float dtheta = 6.2831855f / 48.0f; // f32(2*pi)/48, jax linspace
        const float theta  = (float)a * dtheta;
        float2 cs;
        cs.x = (float)cos((double)theta);
        cs.y = (float)sin((double)theta);
        trig[a] = cs;
    }
}

// ---------------- shared geometry (b-independent) -------------------------
__device__ __forceinline__ void ray_setup_cs(
    int ridx, float c, float s, float& srcx, float& srcy,
    float& dx, float& dy, float& dz, int& k0, int& k1) {
#pragma clang fp contract(off)
    const int u   = ridx % NUg;
    int tmp       = ridx / NUg;
    const int v   = tmp % NVg;

    srcx = 500.0f * c;
    srcy = 500.0f * s;
    const float uu = ((float)u - 47.5f) * 2.0f;
    const float vv = ((float)v - 47.5f) * 2.0f;
    const float pixx = (-500.0f * c) + uu * (-s);
    const float pixy = (-500.0f * s) + uu * c;
    const float pixz = vv;

    const float dx0 = pixx - srcx;
    const float dy0 = pixy - srcy;
    const float dz0 = pixz;
    const float nrm = sqrtf((dx0 * dx0 + dy0 * dy0) + dz0 * dz0);
    dx = dx0 / nrm;
    dy = dy0 / nrm;
    dz = dz0 / nrm;

    const float stepf = (float)1.7320508075688773;   // f32(2R/96)
    const float t0f   = (float)416.8615612366939;    // f32(DSO-R)

    // conservative AABB clip (skip-only; in-loop test is authoritative)
    const float LO = -47.51f, HI = 47.51f;
    float tlo = -1e30f, thi = 1e30f;
    {
        const float o3[3] = {srcx, srcy, 0.0f};
        const float d3[3] = {dx, dy, dz};
        bool empty = false;
        #pragma unroll
        for (int ax = 0; ax < 3; ++ax) {
            const float oo = o3[ax], dd = d3[ax];
            if (fabsf(dd) > 1e-8f) {
                const float inv = 1.0f / dd;
                const float ta = (LO - oo) * inv;
                const float tb = (HI - oo) * inv;
                tlo = fmaxf(tlo, fminf(ta, tb));
                thi = fminf(thi, fmaxf(ta, tb));
            } else if (oo < LO || oo > HI) {
                empty = true;
            }
        }
        if (empty) { tlo = 1.0f; thi = 0.0f; }
    }
    if (thi >= tlo) {
        k0 = (int)floorf((tlo - t0f) / stepf) - 2;
        k1 = (int)ceilf((thi - t0f) / stepf) + 2;
        k0 = max(k0, 0);
        k1 = min(k1, NSg - 1);
    } else {
        k0 = 1; k1 = 0;
    }
}

// ---------------- projection loop body (R13, shared by fused/split) -------
__device__ __forceinline__ void project_ray(
    int ridx, float2 cs, const float2* __restrict__ qx,
    const float2* __restrict__ qy, float* __restrict__ out) {
#pragma clang fp contract(off)
    float srcx, srcy, dx, dy, dz;
    int k0, k1;
    ray_setup_cs(ridx, cs.x, cs.y, srcx, srcy, dx, dy, dz, k0, k1);

    const float stepf = (float)1.7320508075688773;
    const float t0f   = (float)416.8615612366939;

    // Layout select (uniform per block): u_ax = (-s, c, 0).
    // |s| >= |c|  => lanes walk x fastest => x-fast layout.
    const bool xfast = fabsf(cs.y) >= fabsf(cs.x);
    const float2* __restrict__ q = xfast ? qx : qy;
    const float src_i = xfast ? srcx : srcy;
    const float d_i   = xfast ? dx   : dy;
    const float src_m = xfast ? srcy : srcx;
    const float d_m   = xfast ? dy   : dx;

    float acc0 = 0.0f, acc1 = 0.0f;
    for (int k = k0; k <= k1; ++k) {
        const float tk = t0f + ((float)k + 0.5f) * stepf;
        const float ci = (src_i + d_i * tk) + 47.5f;   // inner coord (x or y)
        const float cm = (src_m + d_m * tk) + 47.5f;   // mid coord   (y or x)
        const float iz = (dz * tk) + 47.5f;
        if (ci >= 0.0f && ci <= 95.0f &&
            cm >= 0.0f && cm <= 95.0f &&
            iz >= 0.0f && iz <= 95.0f) {
            const int i0 = min((int)ci, 94);
            const int m0 = min((int)cm, 94);
            const int z0 = min((int)iz, NZg - 2);
            const float fi = ci - (float)i0;
            const float fm = cm - (float)m0;
            const float fz = iz - (float)z0;
            const int base = (z0 * 96 + m0) * 96 + i0;
            // 4 x 16B gathers: each row-load gives (b0@i0,b1@i0,b0@i1,b1@i1)
            const v4f r00 = *(const v4f*)(q + base);                // (m0,z0)
            const v4f r01 = *(const v4f*)(q + base + 96);           // (m1,z0)
            const v4f r10 = *(const v4f*)(q + base + PLANE);        // (m0,z1)
            const v4f r11 = *(const v4f*)(q + base + PLANE + 96);   // (m1,z1)
            // batch 0: .x = b0@i0, .z = b0@i1
            {
                const float c00 = r00.x + fi * (r00.z - r00.x);
                const float c01 = r01.x + fi * (r01.z - r01.x);
                const float c10 = r10.x + fi * (r10.z - r10.x);
                const float c11 = r11.x + fi * (r11.z - r11.x);
                const float c0  = c00 + fm * (c01 - c00);
                const float c1  = c10 + fm * (c11 - c10);
                acc0 += c0 + fz * (c1 - c0);
            }
            // batch 1: .y = b1@i0, .w = b1@i1
            {
                const float c00 = r00.y + fi * (r00.w - r00.y);
                const float c01 = r01.y + fi * (r01.w - r01.y);
                const float c10 = r10.y + fi * (r10.w - r10.y);
                const float c11 = r11.y + fi * (r11.w - r11.y);
                const float c0  = c00 + fm * (c01 - c00);
                const float c1  = c10 + fm * (c11 - c10);
                acc1 += c0 + fz * (c1 - c0);
            }
        }
    }
    out[ridx]         = acc0 * stepf;
    out[ridx + NRAY1] = acc1 * stepf;
}

// ---------------- fused cooperative kernel: pack + sync + project ---------
__global__ __launch_bounds__(256) void coneproj_fused(
    const float* __restrict__ vol, float2* __restrict__ qx,
    float2* __restrict__ qy, const float2* __restrict__ trig,
    float* __restrict__ out) {
    __shared__ float2 tile[16][17];             // +1 pad: no bank conflicts

    // ---- phase A: pack both layouts (2 transpose tiles per block) ----
    const int tx = threadIdx.x & 15;
    const int ty = threadIdx.x >> 4;
    for (int pb = blockIdx.x; pb < 96 * 36; pb += NBLK) {
        const int z      = pb / 36;
        const int tileId = pb % 36;
        const int y0 = (tileId / 6) * 16;
        const int x0 = (tileId % 6) * 16;
        const int idx = (z * NYg + (y0 + ty)) * NXg + (x0 + tx);
        float2 p;
        p.x = vol[idx];
        p.y = vol[idx + NVOX];
        qx[idx] = p;                             // x-fast (coalesced)
        __syncthreads();                         // protect tile vs prev iter
        tile[ty][tx] = p;
        __syncthreads();
        // transposed write: consecutive tx -> consecutive y (coalesced)
        qy[(z * NXg + (x0 + ty)) * NYg + (y0 + tx)] = tile[tx][ty];
    }

    cg::this_grid().sync();

    // ---- phase B: projection, one ray per thread (R13 body) ----
    const int ridx = blockIdx.x * 256 + threadIdx.x;   // (a*96+v)*96+u
    const int a    = ridx / (NUg * NVg);               // uniform per block
    project_ray(ridx, trig[a], qx, qy, out);
}

// ---------------- split-path kernels (fallback, measured R13/R14) ---------
__global__ __launch_bounds__(256) void pack_b2_dual_t(
    const float* __restrict__ vol, float2* __restrict__ qx,
    float2* __restrict__ qy) {
    __shared__ float2 tile[16][17];
    const int z      = blockIdx.x / 36;
    const int tileId = blockIdx.x % 36;
    const int y0 = (tileId / 6) * 16;
    const int x0 = (tileId % 6) * 16;
    const int tx = threadIdx.x & 15;
    const int ty = threadIdx.x >> 4;
    const int idx = (z * NYg + (y0 + ty)) * NXg + (x0 + tx);
    float2 p;
    p.x = vol[idx];
    p.y = vol[idx + NVOX];
    qx[idx] = p;
    tile[ty][tx] = p;
    __syncthreads();
    qy[(z * NXg + (x0 + ty)) * NYg + (y0 + tx)] = tile[tx][ty];
}

__global__ __launch_bounds__(256) void coneproj_b2dual(
    const float2* __restrict__ qx, const float2* __restrict__ qy,
    const float2* __restrict__ trig, float* __restrict__ out) {
    const int ridx = blockIdx.x * blockDim.x + threadIdx.x;
    const int a    = ridx / (NUg * NVg);
    project_ray(ridx, trig[a], qx, qy, out);
}

// ---------------- fallback: direct 8-gather projector (R2) ----------------
__device__ __forceinline__ void ray_setup(
    int ridx, float& srcx, float& srcy, float& dx, float& dy, float& dz,
    int& k0, int& k1) {
#pragma clang fp contract(off)
    const int a = ridx / (NUg * NVg);
    const float dtheta = 6.2831855f / 48.0f;
    const float theta  = (float)a * dtheta;
    const float c = (float)cos((double)theta);
    const float s = (float)sin((double)theta);
    ray_setup_cs(ridx, c, s, srcx, srcy, dx, dy, dz, k0, k1);
}

__global__ __launch_bounds__(256) void coneproj_direct(
    const float* __restrict__ vol, float* __restrict__ out) {
#pragma clang fp contract(off)
    const int gidx = blockIdx.x * blockDim.x + threadIdx.x;  // includes b
    const int ridx = gidx % NRAY1;
    const int b    = gidx / NRAY1;
    float srcx, srcy, dx, dy, dz;
    int k0, k1;
    ray_setup(ridx, srcx, srcy, dx, dy, dz, k0, k1);

    const float stepf = (float)1.7320508075688773;
    const float t0f   = (float)416.8615612366939;

    const float* __restrict__ volb = vol + (size_t)b * NVOX;

    float acc = 0.0f;
    for (int k = k0; k <= k1; ++k) {
        const float tk = t0f + ((float)k + 0.5f) * stepf;
        const float ix = (srcx + dx * tk) + 47.5f;
        const float iy = (srcy + dy * tk) + 47.5f;
        const float iz = (dz * tk) + 47.5f;
        if (ix >= 0.0f && ix <= 95.0f &&
            iy >= 0.0f && iy <= 95.0f &&
            iz >= 0.0f && iz <= 95.0f) {
            const int x0 = min((int)ix, NXg - 2);
            const int y0 = min((int)iy, NYg - 2);
            const int z0 = min((int)iz, NZg - 2);
            const float fx = ix - (float)x0;
            const float fy = iy - (float)y0;
            const float fz = iz - (float)z0;
            const float* p = volb + ((z0 * NYg + y0) * NXg + x0);
            const float v000 = p[0];
            const float v001 = p[1];
            const float v010 = p[NXg];
            const float v011 = p[NXg + 1];
            const float v100 = p[NYg * NXg];
            const float v101 = p[NYg * NXg + 1];
            const float v110 = p[NYg * NXg + NXg];
            const float v111 = p[NYg * NXg + NXg + 1];
            const float c00 = v000 + fx * (v001 - v000);
            const float c01 = v010 + fx * (v011 - v010);
            const float c10 = v100 + fx * (v101 - v100);
            const float c11 = v110 + fx * (v111 - v110);
            const float c0  = c00 + fy * (c01 - c00);
            const float c1  = c10 + fy * (c11 - c10);
            acc += c0 + fz * (c1 - c0);
        }
    }
    out[gidx] = acc * stepf;
}

extern "C" void kernel_launch(void* const* d_in, const int* in_sizes, int n_in,
                              void* d_out, int out_size, void* d_ws, size_t ws_size,
                              hipStream_t stream) {
    const float* vol = (const float*)d_in[0];
    float* out = (float*)d_out;
    const size_t need_dual   = 2 * (size_t)NVOX * sizeof(float2)
                             + (size_t)NAg * sizeof(float2);   // ~14.2 MB
    const size_t need_single = (size_t)NVOX * sizeof(float2);  // ~7.08 MB
    if (ws_size >= need_dual) {
        float2* qx   = (float2*)d_ws;
        float2* qy   = qx + NVOX;
        float2* trig = qy + NVOX;
        make_trig<<<1, 64, 0, stream>>>(trig);
        void* args[] = {(void*)&vol, (void*)&qx, (void*)&qy,
                        (void*)&trig, (void*)&out};
        hipError_t e = hipLaunchCooperativeKernel(
            (void*)coneproj_fused, dim3(NBLK), dim3(256), args, 0, stream);
        if (e != hipSuccess) {
            // fallback: measured R13/R14 split path
            pack_b2_dual_t<<<96 * 36, 256, 0, stream>>>(vol, qx, qy);
            coneproj_b2dual<<<NRAY1 / 256, 256, 0, stream>>>(qx, qy, trig, out);
        }
    } else if (ws_size >= need_single) {
        // single-layout path would need its own pack; use direct projector
        coneproj_direct<<<(NBg * NRAY1) / 256, 256, 0, stream>>>(vol, out);
    } else {
        coneproj_direct<<<(NBg * NRAY1) / 256, 256, 0, stream>>>(vol, out);
    }
}

// Round 6
// 306.803 us; speedup vs baseline: 1.2953x; 1.2953x over previous
//
#include <hip/hip_runtime.h>
#include <math.h>

// Cone-beam forward projection (TIGRE Ax analogue).
// Volume: [B=2, NZ=96, NY=96, NX=96] f32, ZYX layout (x fastest).
// Output: [B=2, A=48, NV=96, NU=96] f32.
//
// R16: R15's cooperative fusion REVERTED (grid.sync forces cross-XCD
// coherence on the gather phase: 330us vs 137us split -- never fuse
// producer/consumer across the XCD boundary for gather consumers).
// New: 6-layout pack. Wave-lane drift ratio (dm/dl)/(di/dl) = -cot(theta)
// (x-inner) / -tan(theta) (y-inner) is EXACT and constant per angle.
// Oblique angles (|ratio|>0.5, 20 of 48) gather from DIAGONAL layouts:
// row r=(m-/+i)%96, 16B entries holding the batch-interleaved i-pair
// (b0@i,b1@i,b0@i+1,b1@i+1). Residual lane row-drift <=0.5/lane =>
// oblique lines/gather ~54 -> ~21. Same 4x16B loads, same lerp register
// semantics -> bit-identical values. ws-guarded: falls back to measured
// R13/R14 dual path (190us) then direct.
//
// CORRECTNESS-CRITICAL: reference integrand is DISCONTINUOUS at cube faces.
// Position path replicates the reference's f32 op sequence exactly:
// contract(off), per-sample src + d*t, IEEE sqrt+div, f64-rounded trig.

#define NZg 96
#define NYg 96
#define NXg 96
#define NVg 96
#define NUg 96
#define NAg 48
#define NSg 96
#define NBg 2
#define NVOX (NZg * NYg * NXg)          // 884736 voxels per batch
#define NRAY1 (NAg * NVg * NUg)         // 442368 rays per batch
#define PLANE (NYg * NXg)               // 9216 entries per z-plane

typedef float v4f __attribute__((ext_vector_type(4)));  // 16B align

// ---------------- staging: 6 layouts + trig, one kernel -------------------
__global__ __launch_bounds__(256) void pack_b2_six(
    const float* __restrict__ vol, float2* __restrict__ qx,
    float2* __restrict__ qy, v4f* __restrict__ DPx, v4f* __restrict__ DMx,
    v4f* __restrict__ DPy, v4f* __restrict__ DMy, float2* __restrict__ trig) {
    const int i = blockIdx.x * 256 + threadIdx.x;         // [z][y][x]
    const int x = i % NXg;
    const int t = i / NXg;
    const int y = t % NYg;
    const int z = t / NYg;
    const float b0 = vol[i];
    const float b1 = vol[i + NVOX];
    float2 p;
    p.x = b0; p.y = b1;
    qx[i] = p;                                  // x-fast [z][y][x]
    qy[(z * NXg + x) * NYg + y] = p;            // y-fast [z][x][y]
    // neighbor values for duplicated i-pairs (entry j=95 never read: i0<=94)
    const float b0x1 = (x < 95) ? vol[i + 1] : 0.0f;
    const float b1x1 = (x < 95) ? vol[i + 1 + NVOX] : 0.0f;
    const float b0y1 = (y < 95) ? vol[i + NXg] : 0.0f;
    const float b1y1 = (y < 95) ? vol[i + NXg + NVOX] : 0.0f;
    v4f px; px.x = b0; px.y = b1; px.z = b0x1; px.w = b1x1;  // i-pair along x
    v4f py; py.x = b0; py.y = b1; py.z = b0y1; py.w = b1y1;  // i-pair along y
    // diagonal rows (all operands non-negative before %)
    const int rpx = (y - x + 96) % 96;          // P, x-inner: m - i
    const int rmx = (y + x) % 96;               // M, x-inner: m + i
    const int rpy = (x - y + 96) % 96;          // P, y-inner
    const int rmy = (x + y) % 96;               // M, y-inner
    DPx[(z * 96 + rpx) * 96 + x] = px;
    DMx[(z * 96 + rmx) * 96 + x] = px;
    DPy[(z * 96 + rpy) * 96 + y] = py;
    DMy[(z * 96 + rmy) * 96 + y] = py;
    if (i < NAg) {                              // 48-entry trig table
        const float dtheta = 6.2831855f / 48.0f; // f32(2*pi)/48, jax linspace
        const float theta  = (float)i * dtheta;
        float2 cs;
        cs.x = (float)cos((double)theta);
        cs.y = (float)sin((double)theta);
        trig[i] = cs;
    }
}

// ---------------- shared geometry (b-independent) -------------------------
__device__ __forceinline__ void ray_setup_cs(
    int ridx, float c, float s, float& srcx, float& srcy,
    float& dx, float& dy, float& dz, int& k0, int& k1) {
#pragma clang fp contract(off)
    const int u   = ridx % NUg;
    int tmp       = ridx / NUg;
    const int v   = tmp % NVg;

    srcx = 500.0f * c;
    srcy = 500.0f * s;
    const float uu = ((float)u - 47.5f) * 2.0f;
    const float vv = ((float)v - 47.5f) * 2.0f;
    const float pixx = (-500.0f * c) + uu * (-s);
    const float pixy = (-500.0f * s) + uu * c;
    const float pixz = vv;

    const float dx0 = pixx - srcx;
    const float dy0 = pixy - srcy;
    const float dz0 = pixz;
    const float nrm = sqrtf((dx0 * dx0 + dy0 * dy0) + dz0 * dz0);
    dx = dx0 / nrm;
    dy = dy0 / nrm;
    dz = dz0 / nrm;

    const float stepf = (float)1.7320508075688773;   // f32(2R/96)
    const float t0f   = (float)416.8615612366939;    // f32(DSO-R)

    // conservative AABB clip (skip-only; in-loop test is authoritative)
    const float LO = -47.51f, HI = 47.51f;
    float tlo = -1e30f, thi = 1e30f;
    {
        const float o3[3] = {srcx, srcy, 0.0f};
        const float d3[3] = {dx, dy, dz};
        bool empty = false;
        #pragma unroll
        for (int ax = 0; ax < 3; ++ax) {
            const float oo = o3[ax], dd = d3[ax];
            if (fabsf(dd) > 1e-8f) {
                const float inv = 1.0f / dd;
                const float ta = (LO - oo) * inv;
                const float tb = (HI - oo) * inv;
                tlo = fmaxf(tlo, fminf(ta, tb));
                thi = fminf(thi, fmaxf(ta, tb));
            } else if (oo < LO || oo > HI) {
                empty = true;
            }
        }
        if (empty) { tlo = 1.0f; thi = 0.0f; }
    }
    if (thi >= tlo) {
        k0 = (int)floorf((tlo - t0f) / stepf) - 2;
        k1 = (int)ceilf((thi - t0f) / stepf) + 2;
        k0 = max(k0, 0);
        k1 = min(k1, NSg - 1);
    } else {
        k0 = 1; k1 = 0;
    }
}

// ---------------- main: 6-layout select, 1 thread per ray -----------------
__global__ __launch_bounds__(256) void coneproj_b2six(
    const float2* __restrict__ qx, const float2* __restrict__ qy,
    const v4f* __restrict__ DPx, const v4f* __restrict__ DMx,
    const v4f* __restrict__ DPy, const v4f* __restrict__ DMy,
    const float2* __restrict__ trig, float* __restrict__ out) {
#pragma clang fp contract(off)
    const int ridx = blockIdx.x * blockDim.x + threadIdx.x;  // (a*96+v)*96+u
    const int a    = ridx / (NUg * NVg);        // uniform per block
    const float2 cs = trig[a];

    float srcx, srcy, dx, dy, dz;
    int k0, k1;
    ray_setup_cs(ridx, cs.x, cs.y, srcx, srcy, dx, dy, dz, k0, k1);

    const float stepf = (float)1.7320508075688773;
    const float t0f   = (float)416.8615612366939;

    // inner-axis select (uniform per block): lanes walk the axis with the
    // larger |u_ax| component. u_ax = (-s, c, 0).
    const bool xfast = fabsf(cs.y) >= fabsf(cs.x);
    const float src_i = xfast ? srcx : srcy;
    const float d_i   = xfast ? dx   : dy;
    const float src_m = xfast ? srcy : srcx;
    const float d_m   = xfast ? dy   : dx;

    // lane drift ratio (dm/dl)/(di/dl): exact per angle.
    // x-inner: -c/s (|s|>=0.707, safe); y-inner: -s/c.
    const float ratio = xfast ? (-cs.x / cs.y) : (-cs.y / cs.x);
    const int mode = (ratio > 0.5f) ? 1 : ((ratio < -0.5f) ? 2 : 0);

    float acc0 = 0.0f, acc1 = 0.0f;

    if (mode == 0) {
        // ---- plain path (R13/R14 body, bit-identical) ----
        const float2* __restrict__ q = xfast ? qx : qy;
        for (int k = k0; k <= k1; ++k) {
            const float tk = t0f + ((float)k + 0.5f) * stepf;
            const float ci = (src_i + d_i * tk) + 47.5f;
            const float cm = (src_m + d_m * tk) + 47.5f;
            const float iz = (dz * tk) + 47.5f;
            if (ci >= 0.0f && ci <= 95.0f &&
                cm >= 0.0f && cm <= 95.0f &&
                iz >= 0.0f && iz <= 95.0f) {
                const int i0 = min((int)ci, 94);
                const int m0 = min((int)cm, 94);
                const int z0 = min((int)iz, NZg - 2);
                const float fi = ci - (float)i0;
                const float fm = cm - (float)m0;
                const float fz = iz - (float)z0;
                const int base = (z0 * 96 + m0) * 96 + i0;
                const v4f r00 = *(const v4f*)(q + base);
                const v4f r01 = *(const v4f*)(q + base + 96);
                const v4f r10 = *(const v4f*)(q + base + PLANE);
                const v4f r11 = *(const v4f*)(q + base + PLANE + 96);
                {
                    const float c00 = r00.x + fi * (r00.z - r00.x);
                    const float c01 = r01.x + fi * (r01.z - r01.x);
                    const float c10 = r10.x + fi * (r10.z - r10.x);
                    const float c11 = r11.x + fi * (r11.z - r11.x);
                    const float c0  = c00 + fm * (c01 - c00);
                    const float c1  = c10 + fm * (c11 - c10);
                    acc0 += c0 + fz * (c1 - c0);
                }
                {
                    const float c00 = r00.y + fi * (r00.w - r00.y);
                    const float c01 = r01.y + fi * (r01.w - r01.y);
                    const float c10 = r10.y + fi * (r10.w - r10.y);
                    const float c11 = r11.y + fi * (r11.w - r11.y);
                    const float c0  = c00 + fm * (c01 - c00);
                    const float c1  = c10 + fm * (c11 - c10);
                    acc1 += c0 + fz * (c1 - c0);
                }
            }
        }
    } else {
        // ---- diagonal path: same values, sheared addressing ----
        const v4f* __restrict__ D =
            xfast ? ((mode == 1) ? DPx : DMx)
                  : ((mode == 1) ? DPy : DMy);
        const bool isP = (mode == 1);
        for (int k = k0; k <= k1; ++k) {
            const float tk = t0f + ((float)k + 0.5f) * stepf;
            const float ci = (src_i + d_i * tk) + 47.5f;
            const float cm = (src_m + d_m * tk) + 47.5f;
            const float iz = (dz * tk) + 47.5f;
            if (ci >= 0.0f && ci <= 95.0f &&
                cm >= 0.0f && cm <= 95.0f &&
                iz >= 0.0f && iz <= 95.0f) {
                const int i0 = min((int)ci, 94);
                const int m0 = min((int)cm, 94);
                const int z0 = min((int)iz, NZg - 2);
                const float fi = ci - (float)i0;
                const float fm = cm - (float)m0;
                const float fz = iz - (float)z0;
                const int rbase = isP ? (m0 - i0 + 96) : (m0 + i0);
                const int r0 = rbase % 96;
                const int r1 = (rbase + 1) % 96;
                const int b00 = (z0 * 96 + r0) * 96 + i0;
                const int b01 = (z0 * 96 + r1) * 96 + i0;
                // entry = (b0@(m,i0), b1@(m,i0), b0@(m,i0+1), b1@(m,i0+1))
                const v4f r00 = D[b00];                 // (m0,z0)
                const v4f r01 = D[b01];                 // (m1,z0)
                const v4f r10 = D[b00 + PLANE];         // (m0,z1)
                const v4f r11 = D[b01 + PLANE];         // (m1,z1)
                {
                    const float c00 = r00.x + fi * (r00.z - r00.x);
                    const float c01 = r01.x + fi * (r01.z - r01.x);
                    const float c10 = r10.x + fi * (r10.z - r10.x);
                    const float c11 = r11.x + fi * (r11.z - r11.x);
                    const float c0  = c00 + fm * (c01 - c00);
                    const float c1  = c10 + fm * (c11 - c10);
                    acc0 += c0 + fz * (c1 - c0);
                }
                {
                    const float c00 = r00.y + fi * (r00.w - r00.y);
                    const float c01 = r01.y + fi * (r01.w - r01.y);
                    const float c10 = r10.y + fi * (r10.w - r10.y);
                    const float c11 = r11.y + fi * (r11.w - r11.y);
                    const float c0  = c00 + fm * (c01 - c00);
                    const float c1  = c10 + fm * (c11 - c10);
                    acc1 += c0 + fz * (c1 - c0);
                }
            }
        }
    }

    out[ridx]         = acc0 * stepf;
    out[ridx + NRAY1] = acc1 * stepf;
}

// ---------------- fallback tier: measured R13/R14 dual path ---------------
__global__ __launch_bounds__(256) void pack_b2_dual_t(
    const float* __restrict__ vol, float2* __restrict__ qx,
    float2* __restrict__ qy) {
    __shared__ float2 tile[16][17];
    const int z      = blockIdx.x / 36;
    const int tileId = blockIdx.x % 36;
    const int y0 = (tileId / 6) * 16;
    const int x0 = (tileId % 6) * 16;
    const int tx = threadIdx.x & 15;
    const int ty = threadIdx.x >> 4;
    const int idx = (z * NYg + (y0 + ty)) * NXg + (x0 + tx);
    float2 p;
    p.x = vol[idx];
    p.y = vol[idx + NVOX];
    qx[idx] = p;
    tile[ty][tx] = p;
    __syncthreads();
    qy[(z * NXg + (x0 + ty)) * NYg + (y0 + tx)] = tile[tx][ty];
}

__global__ void make_trig(float2* __restrict__ trig) {
    const int a = threadIdx.x;
    if (a < NAg) {
        const float dtheta = 6.2831855f / 48.0f;
        const float theta  = (float)a * dtheta;
        float2 cs;
        cs.x = (float)cos((double)theta);
        cs.y = (float)sin((double)theta);
        trig[a] = cs;
    }
}

__global__ __launch_bounds__(256) void coneproj_b2dual(
    const float2* __restrict__ qx, const float2* __restrict__ qy,
    const float2* __restrict__ trig, float* __restrict__ out) {
#pragma clang fp contract(off)
    const int ridx = blockIdx.x * blockDim.x + threadIdx.x;
    const int a    = ridx / (NUg * NVg);
    const float2 cs = trig[a];
    float srcx, srcy, dx, dy, dz;
    int k0, k1;
    ray_setup_cs(ridx, cs.x, cs.y, srcx, srcy, dx, dy, dz, k0, k1);

    const float stepf = (float)1.7320508075688773;
    const float t0f   = (float)416.8615612366939;

    const bool xfast = fabsf(cs.y) >= fabsf(cs.x);
    const float2* __restrict__ q = xfast ? qx : qy;
    const float src_i = xfast ? srcx : srcy;
    const float d_i   = xfast ? dx   : dy;
    const float src_m = xfast ? srcy : srcx;
    const float d_m   = xfast ? dy   : dx;

    float acc0 = 0.0f, acc1 = 0.0f;
    for (int k = k0; k <= k1; ++k) {
        const float tk = t0f + ((float)k + 0.5f) * stepf;
        const float ci = (src_i + d_i * tk) + 47.5f;
        const float cm = (src_m + d_m * tk) + 47.5f;
        const float iz = (dz * tk) + 47.5f;
        if (ci >= 0.0f && ci <= 95.0f &&
            cm >= 0.0f && cm <= 95.0f &&
            iz >= 0.0f && iz <= 95.0f) {
            const int i0 = min((int)ci, 94);
            const int m0 = min((int)cm, 94);
            const int z0 = min((int)iz, NZg - 2);
            const float fi = ci - (float)i0;
            const float fm = cm - (float)m0;
            const float fz = iz - (float)z0;
            const int base = (z0 * 96 + m0) * 96 + i0;
            const v4f r00 = *(const v4f*)(q + base);
            const v4f r01 = *(const v4f*)(q + base + 96);
            const v4f r10 = *(const v4f*)(q + base + PLANE);
            const v4f r11 = *(const v4f*)(q + base + PLANE + 96);
            {
                const float c00 = r00.x + fi * (r00.z - r00.x);
                const float c01 = r01.x + fi * (r01.z - r01.x);
                const float c10 = r10.x + fi * (r10.z - r10.x);
                const float c11 = r11.x + fi * (r11.z - r11.x);
                const float c0  = c00 + fm * (c01 - c00);
                const float c1  = c10 + fm * (c11 - c10);
                acc0 += c0 + fz * (c1 - c0);
            }
            {
                const float c00 = r00.y + fi * (r00.w - r00.y);
                const float c01 = r01.y + fi * (r01.w - r01.y);
                const float c10 = r10.y + fi * (r10.w - r10.y);
                const float c11 = r11.y + fi * (r11.w - r11.y);
                const float c0  = c00 + fm * (c01 - c00);
                const float c1  = c10 + fm * (c11 - c10);
                acc1 += c0 + fz * (c1 - c0);
            }
        }
    }
    out[ridx]         = acc0 * stepf;
    out[ridx + NRAY1] = acc1 * stepf;
}

// ---------------- last-resort: direct 8-gather projector ------------------
__global__ __launch_bounds__(256) void coneproj_direct(
    const float* __restrict__ vol, float* __restrict__ out) {
#pragma clang fp contract(off)
    const int gidx = blockIdx.x * blockDim.x + threadIdx.x;  // includes b
    const int ridx = gidx % NRAY1;
    const int b    = gidx / NRAY1;
    const int a = ridx / (NUg * NVg);
    const float dtheta = 6.2831855f / 48.0f;
    const float theta  = (float)a * dtheta;
    const float c = (float)cos((double)theta);
    const float s = (float)sin((double)theta);
    float srcx, srcy, dx, dy, dz;
    int k0, k1;
    ray_setup_cs(ridx, c, s, srcx, srcy, dx, dy, dz, k0, k1);

    const float stepf = (float)1.7320508075688773;
    const float t0f   = (float)416.8615612366939;

    const float* __restrict__ volb = vol + (size_t)b * NVOX;

    float acc = 0.0f;
    for (int k = k0; k <= k1; ++k) {
        const float tk = t0f + ((float)k + 0.5f) * stepf;
        const float ix = (srcx + dx * tk) + 47.5f;
        const float iy = (srcy + dy * tk) + 47.5f;
        const float iz = (dz * tk) + 47.5f;
        if (ix >= 0.0f && ix <= 95.0f &&
            iy >= 0.0f && iy <= 95.0f &&
            iz >= 0.0f && iz <= 95.0f) {
            const int x0 = min((int)ix, NXg - 2);
            const int y0 = min((int)iy, NYg - 2);
            const int z0 = min((int)iz, NZg - 2);
            const float fx = ix - (float)x0;
            const float fy = iy - (float)y0;
            const float fz = iz - (float)z0;
            const float* p = volb + ((z0 * NYg + y0) * NXg + x0);
            const float v000 = p[0];
            const float v001 = p[1];
            const float v010 = p[NXg];
            const float v011 = p[NXg + 1];
            const float v100 = p[NYg * NXg];
            const float v101 = p[NYg * NXg + 1];
            const float v110 = p[NYg * NXg + NXg];
            const float v111 = p[NYg * NXg + NXg + 1];
            const float c00 = v000 + fx * (v001 - v000);
            const float c01 = v010 + fx * (v011 - v010);
            const float c10 = v100 + fx * (v101 - v100);
            const float c11 = v110 + fx * (v111 - v110);
            const float c0  = c00 + fy * (c01 - c00);
            const float c1  = c10 + fy * (c11 - c10);
            acc += c0 + fz * (c1 - c0);
        }
    }
    out[gidx] = acc * stepf;
}

extern "C" void kernel_launch(void* const* d_in, const int* in_sizes, int n_in,
                              void* d_out, int out_size, void* d_ws, size_t ws_size,
                              hipStream_t stream) {
    const float* vol = (const float*)d_in[0];
    float* out = (float*)d_out;
    // ws layout (full): qx, qy (float2), DPx, DMx, DPy, DMy (v4f), trig
    const size_t need_six  = (size_t)NVOX * (8 + 8 + 4 * 16)
                           + (size_t)NAg * sizeof(float2);   // ~67.5 MiB
    const size_t need_dual = 2 * (size_t)NVOX * sizeof(float2)
                           + (size_t)NAg * sizeof(float2);   // ~14.2 MB
    if (ws_size >= need_six) {
        float2* qx   = (float2*)d_ws;
        float2* qy   = qx + NVOX;
        v4f*    DPx  = (v4f*)(qy + NVOX);
        v4f*    DMx  = DPx + NVOX;
        v4f*    DPy  = DMx + NVOX;
        v4f*    DMy  = DPy + NVOX;
        float2* trig = (float2*)(DMy + NVOX);
        pack_b2_six<<<NVOX / 256, 256, 0, stream>>>(
            vol, qx, qy, DPx, DMx, DPy, DMy, trig);
        coneproj_b2six<<<NRAY1 / 256, 256, 0, stream>>>(
            qx, qy, DPx, DMx, DPy, DMy, trig, out);
    } else if (ws_size >= need_dual) {
        float2* qx   = (float2*)d_ws;
        float2* qy   = qx + NVOX;
        float2* trig = qy + NVOX;
        pack_b2_dual_t<<<96 * 36, 256, 0, stream>>>(vol, qx, qy);
        make_trig<<<1, 64, 0, stream>>>(trig);
        coneproj_b2dual<<<NRAY1 / 256, 256, 0, stream>>>(qx, qy, trig, out);
    } else {
        coneproj_direct<<<(NBg * NRAY1) / 256, 256, 0, stream>>>(vol, out);
    }
}

// Round 7
// 173.710 us; speedup vs baseline: 2.2877x; 1.7662x over previous
//
#include <hip/hip_runtime.h>
#include <math.h>

// Cone-beam forward projection (TIGRE Ax analogue).
// Volume: [B=2, NZ=96, NY=96, NX=96] f32, ZYX layout (x fastest).
// Output: [B=2, A=48, NV=96, NU=96] f32.
//
// R17: R16's sheared layouts REVERTED (shear smears ray tubes across the
// array -> FETCH 48->550MB, 224us; locality must be preserved). New idea:
// exploit v_ax = (0,0,1) EXACTLY. Threads remapped so each wave's 64 lanes
// are 64 consecutive v of one u: lane positions differ ~1 voxel/lane in z
// only (ix,iy drift <=1-2 across the wave, from per-ray normalization).
// Single layout [y][x][z], 16B entries (b0@z,b1@z,b0@z+1,b1@z+1): the 4
// corner loads per sample are rows (y0,x0),(y0,x1),(y1,x0),(y1,x1), each
// one aligned 16B load; a wave spans ~60 consecutive z-entries => ~16-20
// cache lines per gather for EVERY angle (was 29-44, angle-dependent).
// Pure axis relabel -> tube locality preserved (unlike R16's shear).
// Position path & bounds tests bit-identical to reference; lerp order
// z->x->y (value rounding ~1e-6, same class as R13's accepted swap).
// Out-writes are stride-96 scatters: 3.4MB total, negligible.
//
// CORRECTNESS-CRITICAL: reference integrand is DISCONTINUOUS at cube faces.
// Position path replicates the reference's f32 op sequence exactly:
// contract(off), per-sample src + d*t, IEEE sqrt+div, f64-rounded trig.

#define NZg 96
#define NYg 96
#define NXg 96
#define NVg 96
#define NUg 96
#define NAg 48
#define NSg 96
#define NBg 2
#define NVOX (NZg * NYg * NXg)          // 884736 voxels per batch
#define NRAY1 (NAg * NVg * NUg)         // 442368 rays per batch
#define PLANE (NYg * NXg)               // 9216 entries per z-plane (old layouts)

typedef float v4f __attribute__((ext_vector_type(4)));  // 16B align

// ---------------- staging: z-fast dup-pair layout + trig ------------------
// D[(y*96 + x)*96 + z] = (b0@z, b1@z, b0@z+1, b1@z+1); entry z=95 never
// read (z0<=94). Writes coalesced (thread order = [y][x][z]); reads are
// strided but vol (7MB) L2/LLC-resident.
__global__ __launch_bounds__(256) void pack_b2_zfast(
    const float* __restrict__ vol, v4f* __restrict__ D,
    float2* __restrict__ trig) {
    const int j = blockIdx.x * 256 + threadIdx.x;   // [y][x][z] entry index
    const int z = j % NZg;
    const int t = j / NZg;
    const int x = t % NXg;
    const int y = t / NXg;
    const int rd = (z * NYg + y) * NXg + x;         // vol is [z][y][x]
    const float b0 = vol[rd];
    const float b1 = vol[rd + NVOX];
    const float b0n = (z < 95) ? vol[rd + NYg * NXg] : 0.0f;
    const float b1n = (z < 95) ? vol[rd + NYg * NXg + NVOX] : 0.0f;
    v4f e; e.x = b0; e.y = b1; e.z = b0n; e.w = b1n;
    D[j] = e;
    if (j < NAg) {                              // 48-entry trig table
        const float dtheta = 6.2831855f / 48.0f; // f32(2*pi)/48, jax linspace
        const float theta  = (float)j * dtheta;
        float2 cs;
        cs.x = (float)cos((double)theta);
        cs.y = (float)sin((double)theta);
        trig[j] = cs;
    }
}

// ---------------- shared geometry (b-independent) -------------------------
__device__ __forceinline__ void ray_setup_uv(
    int u, int v, float c, float s, float& srcx, float& srcy,
    float& dx, float& dy, float& dz, int& k0, int& k1) {
#pragma clang fp contract(off)
    srcx = 500.0f * c;
    srcy = 500.0f * s;
    const float uu = ((float)u - 47.5f) * 2.0f;
    const float vv = ((float)v - 47.5f) * 2.0f;
    const float pixx = (-500.0f * c) + uu * (-s);
    const float pixy = (-500.0f * s) + uu * c;
    const float pixz = vv;

    const float dx0 = pixx - srcx;
    const float dy0 = pixy - srcy;
    const float dz0 = pixz;
    const float nrm = sqrtf((dx0 * dx0 + dy0 * dy0) + dz0 * dz0);
    dx = dx0 / nrm;
    dy = dy0 / nrm;
    dz = dz0 / nrm;

    const float stepf = (float)1.7320508075688773;   // f32(2R/96)
    const float t0f   = (float)416.8615612366939;    // f32(DSO-R)

    // conservative AABB clip (skip-only; in-loop test is authoritative)
    const float LO = -47.51f, HI = 47.51f;
    float tlo = -1e30f, thi = 1e30f;
    {
        const float o3[3] = {srcx, srcy, 0.0f};
        const float d3[3] = {dx, dy, dz};
        bool empty = false;
        #pragma unroll
        for (int ax = 0; ax < 3; ++ax) {
            const float oo = o3[ax], dd = d3[ax];
            if (fabsf(dd) > 1e-8f) {
                const float inv = 1.0f / dd;
                const float ta = (LO - oo) * inv;
                const float tb = (HI - oo) * inv;
                tlo = fmaxf(tlo, fminf(ta, tb));
                thi = fminf(thi, fmaxf(ta, tb));
            } else if (oo < LO || oo > HI) {
                empty = true;
            }
        }
        if (empty) { tlo = 1.0f; thi = 0.0f; }
    }
    if (thi >= tlo) {
        k0 = (int)floorf((tlo - t0f) / stepf) - 2;
        k1 = (int)ceilf((thi - t0f) / stepf) + 2;
        k0 = max(k0, 0);
        k1 = min(k1, NSg - 1);
    } else {
        k0 = 1; k1 = 0;
    }
}

// ---------------- main: lanes along v, z-fast gathers ---------------------
__global__ __launch_bounds__(256) void coneproj_zfast(
    const v4f* __restrict__ D, const float2* __restrict__ trig,
    float* __restrict__ out) {
#pragma clang fp contract(off)
    const int idx = blockIdx.x * 256 + threadIdx.x;  // (a*96 + u)*96 + v
    const int v   = idx % NVg;
    int tmp       = idx / NVg;
    const int u   = tmp % NUg;
    const int a   = tmp / NUg;                       // uniform per block
    const float2 cs = trig[a];

    float srcx, srcy, dx, dy, dz;
    int k0, k1;
    ray_setup_uv(u, v, cs.x, cs.y, srcx, srcy, dx, dy, dz, k0, k1);

    const float stepf = (float)1.7320508075688773;
    const float t0f   = (float)416.8615612366939;

    float acc0 = 0.0f, acc1 = 0.0f;
    for (int k = k0; k <= k1; ++k) {
        const float tk = t0f + ((float)k + 0.5f) * stepf;
        const float ix = (srcx + dx * tk) + 47.5f;
        const float iy = (srcy + dy * tk) + 47.5f;
        const float iz = (dz * tk) + 47.5f;
        if (ix >= 0.0f && ix <= 95.0f &&
            iy >= 0.0f && iy <= 95.0f &&
            iz >= 0.0f && iz <= 95.0f) {
            const int x0 = min((int)ix, NXg - 2);
            const int y0 = min((int)iy, NYg - 2);
            const int z0 = min((int)iz, NZg - 2);
            const float fx = ix - (float)x0;
            const float fy = iy - (float)y0;
            const float fz = iz - (float)z0;
            const int base = (y0 * NXg + x0) * NZg + z0;
            // 4 x 16B aligned loads; each = z-pair (both batches) at one
            // (y,x) corner. Wave lanes (consecutive v) span consecutive z.
            const v4f r00 = D[base];                     // (y0,x0)
            const v4f r01 = D[base + NZg];               // (y0,x1)
            const v4f r10 = D[base + NXg * NZg];         // (y1,x0)
            const v4f r11 = D[base + NXg * NZg + NZg];   // (y1,x1)
            // batch 0: .x = b0@z0, .z = b0@z1   (lerp order z -> x -> y)
            {
                const float w00 = r00.x + fz * (r00.z - r00.x);
                const float w01 = r01.x + fz * (r01.z - r01.x);
                const float w10 = r10.x + fz * (r10.z - r10.x);
                const float w11 = r11.x + fz * (r11.z - r11.x);
                const float e0  = w00 + fx * (w01 - w00);
                const float e1  = w10 + fx * (w11 - w10);
                acc0 += e0 + fy * (e1 - e0);
            }
            // batch 1: .y = b1@z0, .w = b1@z1
            {
                const float w00 = r00.y + fz * (r00.w - r00.y);
                const float w01 = r01.y + fz * (r01.w - r01.y);
                const float w10 = r10.y + fz * (r10.w - r10.y);
                const float w11 = r11.y + fz * (r11.w - r11.y);
                const float e0  = w00 + fx * (w01 - w00);
                const float e1  = w10 + fx * (w11 - w10);
                acc1 += e0 + fy * (e1 - e0);
            }
        }
    }
    const int oidx = (a * NVg + v) * NUg + u;   // output is [a][v][u]
    out[oidx]         = acc0 * stepf;
    out[oidx + NRAY1] = acc1 * stepf;
}

// ---------------- fallback tier: measured R13/R14 dual path ---------------
__device__ __forceinline__ void ray_setup_cs(
    int ridx, float c, float s, float& srcx, float& srcy,
    float& dx, float& dy, float& dz, int& k0, int& k1) {
    const int u = ridx % NUg;
    const int v = (ridx / NUg) % NVg;
    ray_setup_uv(u, v, c, s, srcx, srcy, dx, dy, dz, k0, k1);
}

__global__ __launch_bounds__(256) void pack_b2_dual_t(
    const float* __restrict__ vol, float2* __restrict__ qx,
    float2* __restrict__ qy) {
    __shared__ float2 tile[16][17];
    const int z      = blockIdx.x / 36;
    const int tileId = blockIdx.x % 36;
    const int y0 = (tileId / 6) * 16;
    const int x0 = (tileId % 6) * 16;
    const int tx = threadIdx.x & 15;
    const int ty = threadIdx.x >> 4;
    const int idx = (z * NYg + (y0 + ty)) * NXg + (x0 + tx);
    float2 p;
    p.x = vol[idx];
    p.y = vol[idx + NVOX];
    qx[idx] = p;
    tile[ty][tx] = p;
    __syncthreads();
    qy[(z * NXg + (x0 + ty)) * NYg + (y0 + tx)] = tile[tx][ty];
}

__global__ void make_trig(float2* __restrict__ trig) {
    const int a = threadIdx.x;
    if (a < NAg) {
        const float dtheta = 6.2831855f / 48.0f;
        const float theta  = (float)a * dtheta;
        float2 cs;
        cs.x = (float)cos((double)theta);
        cs.y = (float)sin((double)theta);
        trig[a] = cs;
    }
}

__global__ __launch_bounds__(256) void coneproj_b2dual(
    const float2* __restrict__ qx, const float2* __restrict__ qy,
    const float2* __restrict__ trig, float* __restrict__ out) {
#pragma clang fp contract(off)
    const int ridx = blockIdx.x * blockDim.x + threadIdx.x;
    const int a    = ridx / (NUg * NVg);
    const float2 cs = trig[a];
    float srcx, srcy, dx, dy, dz;
    int k0, k1;
    ray_setup_cs(ridx, cs.x, cs.y, srcx, srcy, dx, dy, dz, k0, k1);

    const float stepf = (float)1.7320508075688773;
    const float t0f   = (float)416.8615612366939;

    const bool xfast = fabsf(cs.y) >= fabsf(cs.x);
    const float2* __restrict__ q = xfast ? qx : qy;
    const float src_i = xfast ? srcx : srcy;
    const float d_i   = xfast ? dx   : dy;
    const float src_m = xfast ? srcy : srcx;
    const float d_m   = xfast ? dy   : dx;

    float acc0 = 0.0f, acc1 = 0.0f;
    for (int k = k0; k <= k1; ++k) {
        const float tk = t0f + ((float)k + 0.5f) * stepf;
        const float ci = (src_i + d_i * tk) + 47.5f;
        const float cm = (src_m + d_m * tk) + 47.5f;
        const float iz = (dz * tk) + 47.5f;
        if (ci >= 0.0f && ci <= 95.0f &&
            cm >= 0.0f && cm <= 95.0f &&
            iz >= 0.0f && iz <= 95.0f) {
            const int i0 = min((int)ci, 94);
            const int m0 = min((int)cm, 94);
            const int z0 = min((int)iz, NZg - 2);
            const float fi = ci - (float)i0;
            const float fm = cm - (float)m0;
            const float fz = iz - (float)z0;
            const int base = (z0 * 96 + m0) * 96 + i0;
            const v4f r00 = *(const v4f*)(q + base);
            const v4f r01 = *(const v4f*)(q + base + 96);
            const v4f r10 = *(const v4f*)(q + base + PLANE);
            const v4f r11 = *(const v4f*)(q + base + PLANE + 96);
            {
                const float c00 = r00.x + fi * (r00.z - r00.x);
                const float c01 = r01.x + fi * (r01.z - r01.x);
                const float c10 = r10.x + fi * (r10.z - r10.x);
                const float c11 = r11.x + fi * (r11.z - r11.x);
                const float c0  = c00 + fm * (c01 - c00);
                const float c1  = c10 + fm * (c11 - c10);
                acc0 += c0 + fz * (c1 - c0);
            }
            {
                const float c00 = r00.y + fi * (r00.w - r00.y);
                const float c01 = r01.y + fi * (r01.w - r01.y);
                const float c10 = r10.y + fi * (r10.w - r10.y);
                const float c11 = r11.y + fi * (r11.w - r11.y);
                const float c0  = c00 + fm * (c01 - c00);
                const float c1  = c10 + fm * (c11 - c10);
                acc1 += c0 + fz * (c1 - c0);
            }
        }
    }
    out[ridx]         = acc0 * stepf;
    out[ridx + NRAY1] = acc1 * stepf;
}

// ---------------- last-resort: direct 8-gather projector ------------------
__global__ __launch_bounds__(256) void coneproj_direct(
    const float* __restrict__ vol, float* __restrict__ out) {
#pragma clang fp contract(off)
    const int gidx = blockIdx.x * blockDim.x + threadIdx.x;  // includes b
    const int ridx = gidx % NRAY1;
    const int b    = gidx / NRAY1;
    const int a = ridx / (NUg * NVg);
    const float dtheta = 6.2831855f / 48.0f;
    const float theta  = (float)a * dtheta;
    const float c = (float)cos((double)theta);
    const float s = (float)sin((double)theta);
    float srcx, srcy, dx, dy, dz;
    int k0, k1;
    ray_setup_cs(ridx, c, s, srcx, srcy, dx, dy, dz, k0, k1);

    const float stepf = (float)1.7320508075688773;
    const float t0f   = (float)416.8615612366939;

    const float* __restrict__ volb = vol + (size_t)b * NVOX;

    float acc = 0.0f;
    for (int k = k0; k <= k1; ++k) {
        const float tk = t0f + ((float)k + 0.5f) * stepf;
        const float ix = (srcx + dx * tk) + 47.5f;
        const float iy = (srcy + dy * tk) + 47.5f;
        const float iz = (dz * tk) + 47.5f;
        if (ix >= 0.0f && ix <= 95.0f &&
            iy >= 0.0f && iy <= 95.0f &&
            iz >= 0.0f && iz <= 95.0f) {
            const int x0 = min((int)ix, NXg - 2);
            const int y0 = min((int)iy, NYg - 2);
            const int z0 = min((int)iz, NZg - 2);
            const float fx = ix - (float)x0;
            const float fy = iy - (float)y0;
            const float fz = iz - (float)z0;
            const float* p = volb + ((z0 * NYg + y0) * NXg + x0);
            const float v000 = p[0];
            const float v001 = p[1];
            const float v010 = p[NXg];
            const float v011 = p[NXg + 1];
            const float v100 = p[NYg * NXg];
            const float v101 = p[NYg * NXg + 1];
            const float v110 = p[NYg * NXg + NXg];
            const float v111 = p[NYg * NXg + NXg + 1];
            const float c00 = v000 + fx * (v001 - v000);
            const float c01 = v010 + fx * (v011 - v010);
            const float c10 = v100 + fx * (v101 - v100);
            const float c11 = v110 + fx * (v111 - v110);
            const float c0  = c00 + fy * (c01 - c00);
            const float c1  = c10 + fy * (c11 - c10);
            acc += c0 + fz * (c1 - c0);
        }
    }
    out[gidx] = acc * stepf;
}

extern "C" void kernel_launch(void* const* d_in, const int* in_sizes, int n_in,
                              void* d_out, int out_size, void* d_ws, size_t ws_size,
                              hipStream_t stream) {
    const float* vol = (const float*)d_in[0];
    float* out = (float*)d_out;
    const size_t need_zf   = (size_t)NVOX * sizeof(v4f)
                           + (size_t)NAg * sizeof(float2);   // ~14.2 MB
    const size_t need_dual = 2 * (size_t)NVOX * sizeof(float2)
                           + (size_t)NAg * sizeof(float2);   // ~14.2 MB
    if (ws_size >= need_zf) {
        v4f*    D    = (v4f*)d_ws;
        float2* trig = (float2*)(D + NVOX);
        pack_b2_zfast<<<NVOX / 256, 256, 0, stream>>>(vol, D, trig);
        coneproj_zfast<<<NRAY1 / 256, 256, 0, stream>>>(D, trig, out);
    } else if (ws_size >= need_dual) {
        float2* qx   = (float2*)d_ws;
        float2* qy   = qx + NVOX;
        float2* trig = qy + NVOX;
        pack_b2_dual_t<<<96 * 36, 256, 0, stream>>>(vol, qx, qy);
        make_trig<<<1, 64, 0, stream>>>(trig);
        coneproj_b2dual<<<NRAY1 / 256, 256, 0, stream>>>(qx, qy, trig, out);
    } else {
        coneproj_direct<<<(NBg * NRAY1) / 256, 256, 0, stream>>>(vol, out);
    }
}

// Round 8
// 155.832 us; speedup vs baseline: 2.5502x; 1.1147x over previous
//
#include <hip/hip_runtime.h>
#include <math.h>

// Cone-beam forward projection (TIGRE Ax analogue).
// Volume: [B=2, NZ=96, NY=96, NX=96] f32, ZYX layout (x fastest).
// Output: [B=2, A=48, NV=96, NU=96] f32.
//
// R18 = R17 (z-fast dup-pair layout [y][x][z], lanes along v, 4x16B loads
// per sample, 108.6us main) + two refinements:
//  (1) wave footprint 32v x 2u (was 64v x 1u): halves each gather row's
//      z-window (~10 lines); the two u-halves share the same z-window and
//      read the same or x-adjacent row => per-instruction lines ~19 -> ~12.
//      Pure lane remap -- every ray's arithmetic is bit-identical.
//  (2) pack via LDS-tiled (x,z) transpose with +1 z-halo: coalesced reads
//      AND writes (R17 pack read at 36KB lane stride).
// Cost model (validated R10/R13/R14/R17): 4 gathers x (16cy addr + lines).
//
// CORRECTNESS-CRITICAL: reference integrand is DISCONTINUOUS at cube faces.
// Position path replicates the reference's f32 op sequence exactly:
// contract(off), per-sample src + d*t, IEEE sqrt+div, f64-rounded trig.
// Lerp order z->x->y (accepted since R13/R17: value rounding ~1e-6,
// in/out decisions untouched).

#define NZg 96
#define NYg 96
#define NXg 96
#define NVg 96
#define NUg 96
#define NAg 48
#define NSg 96
#define NBg 2
#define NVOX (NZg * NYg * NXg)          // 884736 voxels per batch
#define NRAY1 (NAg * NVg * NUg)         // 442368 rays per batch

typedef float v4f __attribute__((ext_vector_type(4)));  // 16B align

// ---------------- staging: z-fast dup-pair layout via LDS transpose -------
// D[(y*96 + x)*96 + z] = (b0@z, b1@z, b0@z+1, b1@z+1); entry z=95 never
// read (z0<=94). Tile (x,z) 16x16 per y-plane; halo row z0+16.
__global__ __launch_bounds__(256) void pack_b2_zfast_t(
    const float* __restrict__ vol, v4f* __restrict__ D,
    float2* __restrict__ trig) {
    __shared__ float2 tile[17][17];     // [zz][xx], +1 pad vs bank conflicts
    const int y  = blockIdx.x / 36;
    const int t  = blockIdx.x % 36;
    const int z0 = (t / 6) * 16;
    const int x0 = (t % 6) * 16;
    const int tx = threadIdx.x & 15;    // x (read) / z (write) within tile
    const int ty = threadIdx.x >> 4;    // z (read) / x (write) within tile
    // coalesced read: vol is [z][y][x]
    const int rd = ((z0 + ty) * NYg + y) * NXg + (x0 + tx);
    float2 p;
    p.x = vol[rd];
    p.y = vol[rd + NVOX];
    tile[ty][tx] = p;
    if (ty == 0) {                      // z-halo row (z0+16)
        float2 h;
        if (z0 + 16 < NZg) {
            const int rh = ((z0 + 16) * NYg + y) * NXg + (x0 + tx);
            h.x = vol[rh];
            h.y = vol[rh + NVOX];
        } else {
            h.x = 0.0f; h.y = 0.0f;     // never read (z0<=94)
        }
        tile[16][tx] = h;
    }
    __syncthreads();
    // coalesced write: entry (y, x0+ty, z0+tx); consecutive tx -> consec z
    const float2 e0 = tile[tx][ty];
    const float2 e1 = tile[tx + 1][ty];
    v4f e; e.x = e0.x; e.y = e0.y; e.z = e1.x; e.w = e1.y;
    D[(y * NXg + (x0 + ty)) * NZg + (z0 + tx)] = e;
    if (blockIdx.x == 0 && threadIdx.x < NAg) {   // 48-entry trig table
        const float dtheta = 6.2831855f / 48.0f;  // f32(2*pi)/48 (jax linspace)
        const float theta  = (float)threadIdx.x * dtheta;
        float2 cs;
        cs.x = (float)cos((double)theta);
        cs.y = (float)sin((double)theta);
        trig[threadIdx.x] = cs;
    }
}

// ---------------- shared geometry (b-independent) -------------------------
__device__ __forceinline__ void ray_setup_uv(
    int u, int v, float c, float s, float& srcx, float& srcy,
    float& dx, float& dy, float& dz, int& k0, int& k1) {
#pragma clang fp contract(off)
    srcx = 500.0f * c;
    srcy = 500.0f * s;
    const float uu = ((float)u - 47.5f) * 2.0f;
    const float vv = ((float)v - 47.5f) * 2.0f;
    const float pixx = (-500.0f * c) + uu * (-s);
    const float pixy = (-500.0f * s) + uu * c;
    const float pixz = vv;

    const float dx0 = pixx - srcx;
    const float dy0 = pixy - srcy;
    const float dz0 = pixz;
    const float nrm = sqrtf((dx0 * dx0 + dy0 * dy0) + dz0 * dz0);
    dx = dx0 / nrm;
    dy = dy0 / nrm;
    dz = dz0 / nrm;

    const float stepf = (float)1.7320508075688773;   // f32(2R/96)
    const float t0f   = (float)416.8615612366939;    // f32(DSO-R)

    // conservative AABB clip (skip-only; in-loop test is authoritative)
    const float LO = -47.51f, HI = 47.51f;
    float tlo = -1e30f, thi = 1e30f;
    {
        const float o3[3] = {srcx, srcy, 0.0f};
        const float d3[3] = {dx, dy, dz};
        bool empty = false;
        #pragma unroll
        for (int ax = 0; ax < 3; ++ax) {
            const float oo = o3[ax], dd = d3[ax];
            if (fabsf(dd) > 1e-8f) {
                const float inv = 1.0f / dd;
                const float ta = (LO - oo) * inv;
                const float tb = (HI - oo) * inv;
                tlo = fmaxf(tlo, fminf(ta, tb));
                thi = fminf(thi, fmaxf(ta, tb));
            } else if (oo < LO || oo > HI) {
                empty = true;
            }
        }
        if (empty) { tlo = 1.0f; thi = 0.0f; }
    }
    if (thi >= tlo) {
        k0 = (int)floorf((tlo - t0f) / stepf) - 2;
        k1 = (int)ceilf((thi - t0f) / stepf) + 2;
        k0 = max(k0, 0);
        k1 = min(k1, NSg - 1);
    } else {
        k0 = 1; k1 = 0;
    }
}

// ---------------- main: wave = 32v x 2u, z-fast gathers -------------------
// Grid: 1728 blocks x 256. Block tile: 8u x 32v of one angle.
//   a  = blk/36;  r = blk%36;  u0 = (r%12)*8;  v0 = (r/12)*32
//   wave w (tid>>6) covers u = u0+2w+(lane>>5), v = v0+(lane&31).
__global__ __launch_bounds__(256) void coneproj_zfast2(
    const v4f* __restrict__ D, const float2* __restrict__ trig,
    float* __restrict__ out) {
#pragma clang fp contract(off)
    const int lane = threadIdx.x & 63;
    const int w    = threadIdx.x >> 6;
    const int a    = blockIdx.x / 36;               // uniform per block
    const int r    = blockIdx.x % 36;
    const int u    = (r % 12) * 8 + w * 2 + (lane >> 5);
    const int v    = (r / 12) * 32 + (lane & 31);
    const float2 cs = trig[a];

    float srcx, srcy, dx, dy, dz;
    int k0, k1;
    ray_setup_uv(u, v, cs.x, cs.y, srcx, srcy, dx, dy, dz, k0, k1);

    const float stepf = (float)1.7320508075688773;
    const float t0f   = (float)416.8615612366939;

    float acc0 = 0.0f, acc1 = 0.0f;
    for (int k = k0; k <= k1; ++k) {
        const float tk = t0f + ((float)k + 0.5f) * stepf;
        const float ix = (srcx + dx * tk) + 47.5f;
        const float iy = (srcy + dy * tk) + 47.5f;
        const float iz = (dz * tk) + 47.5f;
        if (ix >= 0.0f && ix <= 95.0f &&
            iy >= 0.0f && iy <= 95.0f &&
            iz >= 0.0f && iz <= 95.0f) {
            const int x0 = min((int)ix, NXg - 2);
            const int y0 = min((int)iy, NYg - 2);
            const int z0 = min((int)iz, NZg - 2);
            const float fx = ix - (float)x0;
            const float fy = iy - (float)y0;
            const float fz = iz - (float)z0;
            const int base = (y0 * NXg + x0) * NZg + z0;
            // 4 x 16B aligned loads; each = z-pair (both batches) at one
            // (y,x) corner. Half-waves share the z-window; rows same or
            // x-adjacent => ~12 lines/instruction.
            const v4f r00 = D[base];                     // (y0,x0)
            const v4f r01 = D[base + NZg];               // (y0,x1)
            const v4f r10 = D[base + NXg * NZg];         // (y1,x0)
            const v4f r11 = D[base + NXg * NZg + NZg];   // (y1,x1)
            // batch 0: .x = b0@z0, .z = b0@z1   (lerp order z -> x -> y)
            {
                const float w00 = r00.x + fz * (r00.z - r00.x);
                const float w01 = r01.x + fz * (r01.z - r01.x);
                const float w10 = r10.x + fz * (r10.z - r10.x);
                const float w11 = r11.x + fz * (r11.z - r11.x);
                const float e0  = w00 + fx * (w01 - w00);
                const float e1  = w10 + fx * (w11 - w10);
                acc0 += e0 + fy * (e1 - e0);
            }
            // batch 1: .y = b1@z0, .w = b1@z1
            {
                const float w00 = r00.y + fz * (r00.w - r00.y);
                const float w01 = r01.y + fz * (r01.w - r01.y);
                const float w10 = r10.y + fz * (r10.w - r10.y);
                const float w11 = r11.y + fz * (r11.w - r11.y);
                const float e0  = w00 + fx * (w01 - w00);
                const float e1  = w10 + fx * (w11 - w10);
                acc1 += e0 + fy * (e1 - e0);
            }
        }
    }
    const int oidx = (a * NVg + v) * NUg + u;   // output is [a][v][u]
    out[oidx]         = acc0 * stepf;
    out[oidx + NRAY1] = acc1 * stepf;
}

// ---------------- last-resort: direct 8-gather projector ------------------
__global__ __launch_bounds__(256) void coneproj_direct(
    const float* __restrict__ vol, float* __restrict__ out) {
#pragma clang fp contract(off)
    const int gidx = blockIdx.x * blockDim.x + threadIdx.x;  // includes b
    const int ridx = gidx % NRAY1;
    const int b    = gidx / NRAY1;
    const int u    = ridx % NUg;
    const int v    = (ridx / NUg) % NVg;
    const int a    = ridx / (NUg * NVg);
    const float dtheta = 6.2831855f / 48.0f;
    const float theta  = (float)a * dtheta;
    const float c = (float)cos((double)theta);
    const float s = (float)sin((double)theta);
    float srcx, srcy, dx, dy, dz;
    int k0, k1;
    ray_setup_uv(u, v, c, s, srcx, srcy, dx, dy, dz, k0, k1);

    const float stepf = (float)1.7320508075688773;
    const float t0f   = (float)416.8615612366939;

    const float* __restrict__ volb = vol + (size_t)b * NVOX;

    float acc = 0.0f;
    for (int k = k0; k <= k1; ++k) {
        const float tk = t0f + ((float)k + 0.5f) * stepf;
        const float ix = (srcx + dx * tk) + 47.5f;
        const float iy = (srcy + dy * tk) + 47.5f;
        const float iz = (dz * tk) + 47.5f;
        if (ix >= 0.0f && ix <= 95.0f &&
            iy >= 0.0f && iy <= 95.0f &&
            iz >= 0.0f && iz <= 95.0f) {
            const int x0 = min((int)ix, NXg - 2);
            const int y0 = min((int)iy, NYg - 2);
            const int z0 = min((int)iz, NZg - 2);
            const float fx = ix - (float)x0;
            const float fy = iy - (float)y0;
            const float fz = iz - (float)z0;
            const float* p = volb + ((z0 * NYg + y0) * NXg + x0);
            const float v000 = p[0];
            const float v001 = p[1];
            const float v010 = p[NXg];
            const float v011 = p[NXg + 1];
            const float v100 = p[NYg * NXg];
            const float v101 = p[NYg * NXg + 1];
            const float v110 = p[NYg * NXg + NXg];
            const float v111 = p[NYg * NXg + NXg + 1];
            const float c00 = v000 + fx * (v001 - v000);
            const float c01 = v010 + fx * (v011 - v010);
            const float c10 = v100 + fx * (v101 - v100);
            const float c11 = v110 + fx * (v111 - v110);
            const float c0  = c00 + fy * (c01 - c00);
            const float c1  = c10 + fy * (c11 - c10);
            acc += c0 + fy * 0.0f + fz * (c1 - c0);   // keep op order
        }
    }
    out[gidx] = acc * stepf;
}

extern "C" void kernel_launch(void* const* d_in, const int* in_sizes, int n_in,
                              void* d_out, int out_size, void* d_ws, size_t ws_size,
                              hipStream_t stream) {
    const float* vol = (const float*)d_in[0];
    float* out = (float*)d_out;
    const size_t need_zf = (size_t)NVOX * sizeof(v4f)
                         + (size_t)NAg * sizeof(float2);   // ~14.2 MB
    if (ws_size >= need_zf) {
        v4f*    D    = (v4f*)d_ws;
        float2* trig = (float2*)(D + NVOX);
        pack_b2_zfast_t<<<96 * 36, 256, 0, stream>>>(vol, D, trig);
        coneproj_zfast2<<<NRAY1 / 256, 256, 0, stream>>>(D, trig, out);
    } else {
        coneproj_direct<<<(NBg * NRAY1) / 256, 256, 0, stream>>>(vol, out);
    }
}